// Round 7
// baseline (808.020 us; speedup 1.0000x reference)
//
#include <hip/hip_runtime.h>
#include <hip/hip_bf16.h>
#include <stdint.h>

typedef __attribute__((ext_vector_type(4))) float f32x4;
typedef __attribute__((ext_vector_type(8))) short s16x8;
typedef unsigned short u16;
typedef unsigned int u32;

#define BM 128
#define BN 128
#define BK 64

// round-to-nearest-even f32 -> bf16 (bit pattern)
__device__ __forceinline__ u16 f32_to_bf16(float f) {
    uint32_t u = __float_as_uint(f);
    u = u + 0x7FFFu + ((u >> 16) & 1u);
    return (u16)(u >> 16);
}

__device__ __forceinline__ void gld_lds16(const void* g, void* l) {
    __builtin_amdgcn_global_load_lds(
        (const __attribute__((address_space(1))) uint32_t*)g,
        (__attribute__((address_space(3))) uint32_t*)l,
        16, 0, 0);
}

// Prep fusion: one read of the fp32 input produces BOTH the straight
// bf16 form and the transposed bf16 form.
__global__ void stein_prep_sq(const float* __restrict__ in, u16* __restrict__ outB,
                              u16* __restrict__ outT, int N2) {
    __shared__ float tile[32][33];
    const int tx = threadIdx.x, ty = threadIdx.y;     // 32 x 8
    const int c0 = blockIdx.x * 32, r0 = blockIdx.y * 32;
#pragma unroll
    for (int i = 0; i < 32; i += 8) {
        float v = in[(size_t)(r0 + ty + i) * N2 + (c0 + tx)];
        outB[(size_t)(r0 + ty + i) * N2 + (c0 + tx)] = f32_to_bf16(v);
        tile[ty + i][tx] = v;
    }
    __syncthreads();
#pragma unroll
    for (int i = 0; i < 32; i += 8)
        outT[(size_t)(c0 + ty + i) * N2 + (r0 + tx)] = f32_to_bf16(tile[tx][ty + i]);
}

// Rect prep: in is R x C; outB = straight bf16 (R x C); outT = transpose
// (C x R) with row stride ldoT (left half of the K-concat buffers).
__global__ void stein_prep_rect(const float* __restrict__ in, u16* __restrict__ outB,
                                u16* __restrict__ outT, int R, int C, int ldoT) {
    __shared__ float tile[32][33];
    const int tx = threadIdx.x, ty = threadIdx.y;     // 32 x 8
    const int c0 = blockIdx.x * 32, r0 = blockIdx.y * 32;
#pragma unroll
    for (int i = 0; i < 32; i += 8) {
        float v = in[(size_t)(r0 + ty + i) * C + (c0 + tx)];
        outB[(size_t)(r0 + ty + i) * C + (c0 + tx)] = f32_to_bf16(v);
        tile[ty + i][tx] = v;
    }
    __syncthreads();
#pragma unroll
    for (int i = 0; i < 32; i += 8)
        outT[(size_t)(c0 + ty + i) * ldoT + (r0 + tx)] = f32_to_bf16(tile[tx][ty + i]);
}

// Runtime-descriptor GEMM op: C[m,n] = sum_k U[m,k] V[n,k]  (NT, bf16 in).
struct GemmOp {
    const u16* U; const u16* V;
    const float* Add;
    u16* OutB; u16* OutT; float* OutF;
    int K, ldu, ldv, N, ldo;
};

// R19 = R18 structure (128x128x64, 4 waves, 2 blocks/CU, XCD chunking)
// with B TAKEN FROM GLOBAL INTO REGISTERS instead of LDS.
// Model that motivated it: per SIMD per K-tile, 2 waves issue 64 MFMA
// (~310 cyc matrix pipe) but ALSO 2x16 ds_read_b128 (~12 cyc each, m134)
// = 384 cyc LDS-read issue -> ~20% MfmaUtil cap (measured 21%). B-frag
// addresses are 16B-aligned contiguous chunks; two waves + 4 neighbor
// blocks share B panels (L1/L2-resident; global read pattern per block is
// IDENTICAL to the staged version). B-frags for tile t+1 double-buffered
// in named register arrays (static indexing), issued right after tile t's
// barrier (full-tile latency cover; certified by the next barrier's own
// vmcnt drain). Halves LDS traffic: new cap ~60%.
// LDS: A staging 2x16KB + OutT bounce union = 33792 B.
// XCD chunk (square ops): each XCD owns 4bm x 8bn; paired z's map same.
// A bank swizzle (0 conflicts): phys chunk p of row r holds logical
// p ^ (r&7); readers use (s*4+(lane>>4)) ^ (lane&7).
__global__ __launch_bounds__(256, 2) void stein_gemm_nt2(GemmOp op0, GemmOp op1,
                                                         GemmOp op2, GemmOp op3,
                                                         GemmOp op4) {
    const int z = blockIdx.z;
    const GemmOp op = (z == 0) ? op0 : (z == 1) ? op1 : (z == 2) ? op2
                      : (z == 3) ? op3 : op4;
    int bm = blockIdx.x, bn = blockIdx.y;
    if (op.N >= 16 * BN) {                    // square op on a 16x16 grid
        const int orig = (int)blockIdx.x + ((int)blockIdx.y << 4);
        const int xcd = orig & 7, idx = orig >> 3;
        bm = (xcd & 3) * 4 + (idx & 3);       // XCD chunk: bm in [4a,4a+4)
        bn = (xcd >> 2) * 8 + (idx >> 2);     //            bn in [8b,8b+8)
    }
    if (bn * BN >= op.N) return;              // rectangular (N=512) ops

    __shared__ alignas(16) short SMEM[16896];      // 33792 B: Us[2] | bounce
    short* Us0 = SMEM;                             // 2 x BM*BK = 32 KB

    const int t = threadIdx.x;
    const int wave = t >> 6;
    const int lane = t & 63;
    const int wm = (wave >> 1) * 64;
    const int wn = (wave & 1) * 64;

    // A staging: wave w covers rows [32w, 32w+32); 4 DMA ops (8 rows x 128 B).
    const int lrow8 = lane >> 3;                  // 0..7
    const int lchunk = (lane & 7) ^ lrow8;        // swizzled source chunk
    const u16* gU = op.U + (size_t)(bm * BM + wave * 32 + lrow8) * op.ldu + lchunk * 8;
    short* sU = Us0 + (wave * 32) * BK;
    const int bufU = BM * BK;                     // elements per buffer

    // B direct-from-global fragment base: row = bn*BN + wn + (lane&15),
    // k base = (lane>>4)*8; per frag j: +16 rows; per k-step s: +32 elems.
    const u16* gB = op.V + (size_t)(bn * BN + wn + (lane & 15)) * op.ldv + (lane >> 4) * 8;

    f32x4 acc[4][4];
#pragma unroll
    for (int i = 0; i < 4; ++i)
#pragma unroll
        for (int j = 0; j < 4; ++j) acc[i][j] = (f32x4){0.f, 0.f, 0.f, 0.f};

    const int arow = wm + (lane & 15);
    const int NT = op.K / BK;                 // 8 / 16 / 32 — always even

    // prologue: stage A tile 0 -> buf 0; load B tile 0 -> b0 regs
#pragma unroll
    for (int j = 0; j < 4; ++j)
        gld_lds16(gU + (size_t)(8 * j) * op.ldu, sU + j * 512);
    s16x8 b0[4][2], b1[4][2];
#pragma unroll
    for (int j = 0; j < 4; ++j) {
        b0[j][0] = *(const s16x8*)(gB + (size_t)(j * 16) * op.ldv);
        b0[j][1] = *(const s16x8*)(gB + (size_t)(j * 16) * op.ldv + 32);
    }

#define GBODY(T, CUR, NXT) do {                                               \
    __syncthreads();  /* drains tile-T staging + B loads (vmcnt 0) */         \
    if ((T) + 1 < NT) {                                                       \
        const int kn_ = ((T) + 1) * BK;                                       \
        const int bo_ = ((T) + 1) & 1;                                        \
        _Pragma("unroll") for (int j = 0; j < 4; ++j)                         \
            gld_lds16(gU + (size_t)(8 * j) * op.ldu + kn_,                    \
                      sU + bo_ * bufU + j * 512);                             \
        _Pragma("unroll") for (int j = 0; j < 4; ++j) {                       \
            NXT[j][0] = *(const s16x8*)(gB + (size_t)(j * 16) * op.ldv + kn_);\
            NXT[j][1] = *(const s16x8*)(gB + (size_t)(j * 16) * op.ldv + kn_ + 32);\
        }                                                                     \
    }                                                                         \
    {                                                                         \
        const s16x8* Up_ = (const s16x8*)(Us0 + ((T) & 1) * bufU);            \
        _Pragma("unroll") for (int s = 0; s < 2; ++s) {                       \
            const int cx_ = (s * 4 + (lane >> 4)) ^ (lane & 7);               \
            s16x8 af_[4];                                                     \
            _Pragma("unroll") for (int i = 0; i < 4; ++i)                     \
                af_[i] = Up_[(arow + i * 16) * (BK / 8) + cx_];               \
            _Pragma("unroll") for (int i = 0; i < 4; ++i)                     \
                _Pragma("unroll") for (int j = 0; j < 4; ++j)                 \
                    acc[i][j] = __builtin_amdgcn_mfma_f32_16x16x32_bf16(      \
                        af_[i], CUR[j][s], acc[i][j], 0, 0, 0);               \
        }                                                                     \
    }                                                                         \
} while (0)

    for (int tt = 0; tt < NT; tt += 2) {
        GBODY(tt, b0, b1);
        GBODY(tt + 1, b1, b0);
    }
#undef GBODY

    // ---- epilogue ----  C/D layout: col=lane&15, row=(lane>>4)*4+r
    const int ldo = op.ldo;
    const int ccol = lane & 15;
    const int crow = (lane >> 4) * 4;

    // pass 1: row-major outputs straight from registers (+ optional Add)
    if (op.OutB || op.OutF) {
#pragma unroll
        for (int i = 0; i < 4; ++i) {
#pragma unroll
            for (int j = 0; j < 4; ++j) {
                const int gr0 = bm * BM + wm + i * 16 + crow;
                const int gc = bn * BN + wn + j * 16 + ccol;
                float v[4];
#pragma unroll
                for (int r = 0; r < 4; ++r) {
                    v[r] = acc[i][j][r];
                    if (op.Add) v[r] += op.Add[(size_t)(gr0 + r) * ldo + gc];
                }
                if (op.OutB) {
#pragma unroll
                    for (int r = 0; r < 4; ++r)
                        op.OutB[(size_t)(gr0 + r) * ldo + gc] = f32_to_bf16(v[r]);
                }
                if (op.OutF) {
#pragma unroll
                    for (int r = 0; r < 4; ++r)
                        op.OutF[(size_t)(gr0 + r) * ldo + gc] = v[r];
                }
            }
        }
    }

    // pass 2: transposed bf16 via LDS bounce (staging LDS is dead now).
    // T[col][row], stride 132 u16 (bank spread). Coalesced 16 B/lane rows.
    if (op.OutT) {
        __syncthreads();                   // all K-loop LDS reads complete
        u16* T = (u16*)SMEM;               // 128*132*2 = 33792 B exactly
#pragma unroll
        for (int i = 0; i < 4; ++i) {
#pragma unroll
            for (int j = 0; j < 4; ++j) {
                const int c_ = wn + j * 16 + ccol;
                const int r_ = wm + i * 16 + crow;      // multiple of 4
                uint2 w;
                w.x = (u32)f32_to_bf16(acc[i][j][0]) | ((u32)f32_to_bf16(acc[i][j][1]) << 16);
                w.y = (u32)f32_to_bf16(acc[i][j][2]) | ((u32)f32_to_bf16(acc[i][j][3]) << 16);
                *(uint2*)&T[c_ * 132 + r_] = w;
            }
        }
        __syncthreads();
        const int cpart = t >> 4;          // 0..15: column within pass
        const int m = t & 15;              // 16 B chunk along the row
#pragma unroll
        for (int k2 = 0; k2 < 8; ++k2) {
            const int c_ = k2 * 16 + cpart;
            uint2 x = *(const uint2*)&T[c_ * 132 + m * 8];
            uint2 y = *(const uint2*)&T[c_ * 132 + m * 8 + 4];
            uint4 w; w.x = x.x; w.y = x.y; w.z = y.x; w.w = y.y;
            *(uint4*)&op.OutT[(size_t)(bn * BN + c_) * ldo + bm * BM + m * 8] = w;
        }
    }
}

static inline GemmOp mkop(const u16* U, const u16* V, int K, int ldu, int ldv,
                          const float* Add, u16* OutB, u16* OutT, float* OutF,
                          int N = 2048, int ldo = 2048) {
    GemmOp o;
    o.U = U; o.V = V; o.Add = Add; o.OutB = OutB; o.OutT = OutT; o.OutF = OutF;
    o.K = K; o.ldu = ldu; o.ldv = ldv; o.N = N; o.ldo = ldo;
    return o;
}

extern "C" void kernel_launch(void* const* d_in, const int* in_sizes, int n_in,
                              void* d_out, int out_size, void* d_ws, size_t ws_size,
                              hipStream_t stream) {
    const float* A = (const float*)d_in[0];     // (2048, 2048)
    const float* A_F = (const float*)d_in[1];   // (2048, 2048)
    const float* C = (const float*)d_in[2];     // (512, 2048)
    const float* C_F = (const float*)d_in[3];   // (512, 2048)
    const int n = 2048, p = 512;
    (void)in_sizes; (void)n_in; (void)out_size; (void)ws_size;

    char* ws = (char*)d_ws;
    const size_t MB = 1u << 20;
    // ---- Smith squaring, 5 levels -> S_32 (tail bound: see R12 notes;
    // absmax 0.5 measured, threshold 2.33).
    // d0b-fold: R_1 = [CFT|W1] [CT|Y]^T in ONE K=1024 GEMM.
    // R19: XT computed TRANSPOSED-FREE via operand swap:
    //   (R A)^T = NT-GEMM(U = A^T, V = R)  -> plain OutB store.
    u16* AT   = (u16*)(ws + 0 * MB);    // A^T  bf16  (A_0 transposed form)
    u16* Ab   = (u16*)(ws + 8 * MB);    // A    bf16  (A_0 row form)
    u16* AFT  = (u16*)(ws + 16 * MB);   // B=A_F^T row bf16 (B_0 row form)
    u16* AFb  = (u16*)(ws + 24 * MB);   // A_F  bf16  (B_0 transposed form)
    u16* WYU  = (u16*)(ws + 32 * MB);   // 2048x1024: [CFT | W1=B C_F^T]
    u16* WYV  = (u16*)(ws + 36 * MB);   // 2048x1024: [CT  | Y=A^T C^T]
    u16* XT   = (u16*)(ws + 32 * MB);   // (R A_i)^T — overlaps WYU/WYV (dead after d0b)
    float* R32 = (float*)(ws + 40 * MB);// running R fp32
    u16* Rb   = (u16*)(ws + 56 * MB);   // running R bf16 row
    u16* CFb  = (u16*)(ws + 64 * MB);   // C_F bf16 row (level 0 only)
    u16* Cb   = (u16*)(ws + 66 * MB);   // C   bf16 row (level 0 only)
    u16* Tb1  = (u16*)(ws + 68 * MB);   // ping-pong set 1: B_i row
    u16* TbT1 = (u16*)(ws + 76 * MB);   //                  B_i^T
    u16* Ub1  = (u16*)(ws + 84 * MB);   //                  A_i row
    u16* UbT1 = (u16*)(ws + 92 * MB);   //                  A_i^T   (top = 100 MB)

    dim3 tb(32, 8);
    stein_prep_sq<<<dim3(64, 64), tb, 0, stream>>>(A, Ab, AT, n);
    stein_prep_sq<<<dim3(64, 64), tb, 0, stream>>>(A_F, AFb, AFT, n);
    stein_prep_rect<<<dim3(64, 16), tb, 0, stream>>>(C_F, CFb, WYU, p, n, 2 * p);
    stein_prep_rect<<<dim3(64, 16), tb, 0, stream>>>(C, Cb, WYV, p, n, 2 * p);

    u16* Tb[2]  = {AFT, Tb1};
    u16* TbT[2] = {AFb, TbT1};
    u16* Ub[2]  = {Ab, Ub1};
    u16* UbT[2] = {AT, UbT1};

    dim3 blk(256);
    dim3 g1(16, 16, 1), g2(16, 16, 2), g4(16, 16, 4);

    // d0 (z=4): level-0 independent ops. Long K=2048 small-N ops at LOW z
    // (dispatched first) so stragglers are short.
    {
        GemmOp oW1  = mkop(AFT, CFb, n, n, n, nullptr, WYU + p, nullptr, nullptr, p, 2 * p);
        GemmOp oY   = mkop(AT, Cb, n, n, n, nullptr, WYV + p, nullptr, nullptr, p, 2 * p);
        GemmOp oAsq = mkop(Ub[0], UbT[0], n, n, n, nullptr, Ub[1], UbT[1], nullptr);
        GemmOp oBsq = mkop(Tb[0], TbT[0], n, n, n, nullptr, Tb[1], TbT[1], nullptr);
        stein_gemm_nt2<<<g4, blk, 0, stream>>>(oW1, oY, oAsq, oBsq, oBsq);
    }
    // d0b: R_1 = [CFT|W1] [CT|Y]^T  (K=1024 concat = RHS + B RHS A)
    {
        GemmOp oR1 = mkop(WYU, WYV, 2 * p, 2 * p, 2 * p, nullptr, Rb, nullptr, R32);
        stein_gemm_nt2<<<g1, blk, 0, stream>>>(oR1, oR1, oR1, oR1, oR1);
    }

    // levels 1..3: full doubling, stream-sharing pairing.
    // R_j = S_{2^j}; after level 3: R_4 = S_16, A_4 = A^16 in set 0.
    // Level 3 drops dead outputs (level 4 needs only UbT[0] and Tb[0]).
    for (int i = 1; i < 4; ++i) {
        const int c = i & 1, nx = c ^ 1;
        // d1: {XT = (R A_i)^T via swap (U=A_i^T, V=R), Asq = A_i^2}.
        GemmOp oXT = mkop(UbT[c], Rb, n, n, n, nullptr, XT, nullptr, nullptr);
        GemmOp oAsq = mkop(Ub[c], UbT[c], n, n, n, nullptr,
                           (i == 3) ? nullptr : Ub[nx], UbT[nx], nullptr);
        stein_gemm_nt2<<<g2, blk, 0, stream>>>(oXT, oAsq, oAsq, oAsq, oAsq);
        // d2: {Rup = B_i X + R, Bsq = B_i^2} — shared U stream = B_i.
        GemmOp oRup = mkop(Tb[c], XT, n, n, n, R32, Rb, nullptr, R32);
        GemmOp oBsq = mkop(Tb[c], TbT[c], n, n, n, nullptr, Tb[nx],
                           (i == 3) ? nullptr : TbT[nx], nullptr);
        stein_gemm_nt2<<<g2, blk, 0, stream>>>(oRup, oBsq, oBsq, oBsq, oBsq);
    }

    // level 4 (final): S_32 = R_4 + B_4 (R_4 A_4) -> d_out. A_4/B_4 in set 0.
    {
        const int c = 0;
        GemmOp oXT = mkop(UbT[c], Rb, n, n, n, nullptr, XT, nullptr, nullptr);
        stein_gemm_nt2<<<g1, blk, 0, stream>>>(oXT, oXT, oXT, oXT, oXT);
        GemmOp oFin = mkop(Tb[c], XT, n, n, n, R32, nullptr, nullptr, (float*)d_out);
        stein_gemm_nt2<<<g1, blk, 0, stream>>>(oFin, oFin, oFin, oFin, oFin);
    }
}

// Round 8
// 458.704 us; speedup vs baseline: 1.7615x; 1.7615x over previous
//
#include <hip/hip_runtime.h>
#include <hip/hip_bf16.h>
#include <stdint.h>

typedef __attribute__((ext_vector_type(4))) float f32x4;
typedef __attribute__((ext_vector_type(8))) short s16x8;
typedef unsigned short u16;
typedef unsigned int u32;

#define BM 128
#define BK 64

// round-to-nearest-even f32 -> bf16 (bit pattern)
__device__ __forceinline__ u16 f32_to_bf16(float f) {
    uint32_t u = __float_as_uint(f);
    u = u + 0x7FFFu + ((u >> 16) & 1u);
    return (u16)(u >> 16);
}

__device__ __forceinline__ void gld_lds16(const void* g, void* l) {
    __builtin_amdgcn_global_load_lds(
        (const __attribute__((address_space(1))) uint32_t*)g,
        (__attribute__((address_space(3))) uint32_t*)l,
        16, 0, 0);
}

// Prep fusion: one read of the fp32 input produces BOTH the straight
// bf16 form and the transposed bf16 form.
__global__ void stein_prep_sq(const float* __restrict__ in, u16* __restrict__ outB,
                              u16* __restrict__ outT, int N2) {
    __shared__ float tile[32][33];
    const int tx = threadIdx.x, ty = threadIdx.y;     // 32 x 8
    const int c0 = blockIdx.x * 32, r0 = blockIdx.y * 32;
#pragma unroll
    for (int i = 0; i < 32; i += 8) {
        float v = in[(size_t)(r0 + ty + i) * N2 + (c0 + tx)];
        outB[(size_t)(r0 + ty + i) * N2 + (c0 + tx)] = f32_to_bf16(v);
        tile[ty + i][tx] = v;
    }
    __syncthreads();
#pragma unroll
    for (int i = 0; i < 32; i += 8)
        outT[(size_t)(c0 + ty + i) * N2 + (r0 + tx)] = f32_to_bf16(tile[tx][ty + i]);
}

// Rect prep: in is R x C; outB = straight bf16 (R x C); outT = transpose
// (C x R) with row stride ldoT (left half of the K-concat buffers).
__global__ void stein_prep_rect(const float* __restrict__ in, u16* __restrict__ outB,
                                u16* __restrict__ outT, int R, int C, int ldoT) {
    __shared__ float tile[32][33];
    const int tx = threadIdx.x, ty = threadIdx.y;     // 32 x 8
    const int c0 = blockIdx.x * 32, r0 = blockIdx.y * 32;
#pragma unroll
    for (int i = 0; i < 32; i += 8) {
        float v = in[(size_t)(r0 + ty + i) * C + (c0 + tx)];
        outB[(size_t)(r0 + ty + i) * C + (c0 + tx)] = f32_to_bf16(v);
        tile[ty + i][tx] = v;
    }
    __syncthreads();
#pragma unroll
    for (int i = 0; i < 32; i += 8)
        outT[(size_t)(c0 + ty + i) * ldoT + (r0 + tx)] = f32_to_bf16(tile[tx][ty + i]);
}

// Runtime-descriptor GEMM op: C[m,n] = sum_k U[m,k] V[n,k]  (NT, bf16 in).
struct GemmOp {
    const u16* U; const u16* V;
    const float* Add;
    u16* OutB; u16* OutT; float* OutF;
    int K, ldu, ldv, N, ldo;
};

// R20: R18 K-loop verbatim (measured-best: 128-wide M, BK=64, 4 waves,
// staged A AND B — R19's B-from-global was an uncoalesced per-lane gather,
// 121 µs vs 81), templated on BNT (N tile width):
//  - BNT=128: multi-op (z>1) dispatches; 512 blocks = 2 blocks/CU.
//  - BNT=64:  single-op dispatches (d0b, level-4 XT, Fin). These ran at
//    256 blocks = 1 block/CU = 1 wave/SIMD (no latency hiding — the one
//    mechanism that works in this structure). grid (16,32) = 512 blocks
//    restores 2 blocks/CU; LDS 48 KB.
// XCD chunk (square ops): each XCD owns a compact bm x bn chunk; paired
// z's map the same -> shared stream cached once per XCD (R18: FETCH 100->83).
// Epilogue: OutT via LDS bounce (R17: WRITE 61->37 MB); OutT-free ops
// (swapped XT) skip it entirely.
// A/B bank swizzle (0 conflicts measured): phys chunk p of row r holds
// logical chunk p ^ (r&7); readers use (s*4+(lane>>4)) ^ (lane&7).
template <int BNT>
__global__ __launch_bounds__(256, 2) void stein_gemm_nt2(GemmOp op0, GemmOp op1,
                                                         GemmOp op2, GemmOp op3,
                                                         GemmOp op4) {
    constexpr int NJ = BNT / 32;              // acc cols per wave (4 or 2)
    const int z = blockIdx.z;
    const GemmOp op = (z == 0) ? op0 : (z == 1) ? op1 : (z == 2) ? op2
                      : (z == 3) ? op3 : op4;
    int bm = blockIdx.x, bn = blockIdx.y;
    if (op.N >= 16 * BNT) {                   // square op: XCD chunking
        const int orig = (int)blockIdx.x + ((int)blockIdx.y << 4);
        const int xcd = orig & 7, idx = orig >> 3;
        constexpr int BNCH = (BNT == 128) ? 8 : 16;   // bn chunk width
        bm = (xcd & 3) * 4 + (idx & 3);
        bn = (xcd >> 2) * BNCH + (idx >> 2);
    }
    if (bn * BNT >= op.N) return;             // rectangular (N=512) ops

    __shared__ alignas(16) short SMEM[2 * BM * BK + 2 * BNT * BK];
    short* Us0 = SMEM;                        // 2 x BM*BK
    short* Vs0 = SMEM + 2 * BM * BK;          // 2 x BNT*BK

    const int t = threadIdx.x;
    const int wave = t >> 6;
    const int lane = t & 63;
    const int wm = (wave >> 1) * 64;
    const int wn = (wave & 1) * (BNT / 2);

    // staging: wave w covers A rows [32w,32w+32) (4 DMA ops) and B rows
    // [w*BNT/4, +BNT/4) (BNT/32 DMA ops); 8 rows x 128 B per op.
    const int lrow8 = lane >> 3;                  // 0..7
    const int lchunk = (lane & 7) ^ lrow8;        // swizzled source chunk
    const u16* gU = op.U + (size_t)(bm * BM + wave * 32 + lrow8) * op.ldu + lchunk * 8;
    const u16* gV = op.V + (size_t)(bn * BNT + wave * (BNT / 4) + lrow8) * op.ldv + lchunk * 8;
    short* sU = Us0 + (wave * 32) * BK;
    short* sV = Vs0 + (wave * (BNT / 4)) * BK;
    const int bufU = BM * BK;                     // elements per buffer
    const int bufV = BNT * BK;

    f32x4 acc[4][NJ];
#pragma unroll
    for (int i = 0; i < 4; ++i)
#pragma unroll
        for (int j = 0; j < NJ; ++j) acc[i][j] = (f32x4){0.f, 0.f, 0.f, 0.f};

    const int arow = wm + (lane & 15);
    const int brow = wn + (lane & 15);

    // prologue: stage tile 0 into buffer 0
#pragma unroll
    for (int j = 0; j < 4; ++j)
        gld_lds16(gU + (size_t)(8 * j) * op.ldu, sU + j * 512);
#pragma unroll
    for (int j = 0; j < BNT / 32; ++j)
        gld_lds16(gV + (size_t)(8 * j) * op.ldv, sV + j * 512);

    int buf = 0;
    for (int kk = 0; kk < op.K; kk += BK) {
        __syncthreads();   // buffer `buf` staged; prior reads of buf^1 done
        if (kk + BK < op.K) {
            const int kn = kk + BK;
            const int bo = buf ^ 1;
#pragma unroll
            for (int j = 0; j < 4; ++j)
                gld_lds16(gU + (size_t)(8 * j) * op.ldu + kn, sU + bo * bufU + j * 512);
#pragma unroll
            for (int j = 0; j < BNT / 32; ++j)
                gld_lds16(gV + (size_t)(8 * j) * op.ldv + kn, sV + bo * bufV + j * 512);
        }
#pragma unroll
        for (int s = 0; s < 2; ++s) {
            const int cx = (s * 4 + (lane >> 4)) ^ (lane & 7);   // phys chunk
            s16x8 af[4], bfr[NJ];
#pragma unroll
            for (int i = 0; i < 4; ++i)
                af[i] = ((const s16x8*)(Us0 + (size_t)buf * bufU))[(arow + i * 16) * (BK / 8) + cx];
#pragma unroll
            for (int j = 0; j < NJ; ++j)
                bfr[j] = ((const s16x8*)(Vs0 + (size_t)buf * bufV))[(brow + j * 16) * (BK / 8) + cx];
#pragma unroll
            for (int i = 0; i < 4; ++i)
#pragma unroll
                for (int j = 0; j < NJ; ++j)
                    acc[i][j] = __builtin_amdgcn_mfma_f32_16x16x32_bf16(
                        af[i], bfr[j], acc[i][j], 0, 0, 0);
        }
        buf ^= 1;
    }

    // ---- epilogue ----  C/D layout: col=lane&15, row=(lane>>4)*4+r
    const int ldo = op.ldo;
    const int ccol = lane & 15;
    const int crow = (lane >> 4) * 4;

    // pass 1: row-major outputs straight from registers (+ optional Add)
    if (op.OutB || op.OutF) {
#pragma unroll
        for (int i = 0; i < 4; ++i) {
#pragma unroll
            for (int j = 0; j < NJ; ++j) {
                const int gr0 = bm * BM + wm + i * 16 + crow;
                const int gc = bn * BNT + wn + j * 16 + ccol;
                float v[4];
#pragma unroll
                for (int r = 0; r < 4; ++r) {
                    v[r] = acc[i][j][r];
                    if (op.Add) v[r] += op.Add[(size_t)(gr0 + r) * ldo + gc];
                }
                if (op.OutB) {
#pragma unroll
                    for (int r = 0; r < 4; ++r)
                        op.OutB[(size_t)(gr0 + r) * ldo + gc] = f32_to_bf16(v[r]);
                }
                if (op.OutF) {
#pragma unroll
                    for (int r = 0; r < 4; ++r)
                        op.OutF[(size_t)(gr0 + r) * ldo + gc] = v[r];
                }
            }
        }
    }

    // pass 2: transposed bf16 via LDS bounce (staging LDS is dead now).
    // T[col][row], stride 132 u16 (bank spread). Coalesced 16 B/lane rows.
    if (op.OutT) {
        __syncthreads();                   // all K-loop LDS reads complete
        u16* T = (u16*)SMEM;               // BNT*132*2 B <= SMEM
#pragma unroll
        for (int i = 0; i < 4; ++i) {
#pragma unroll
            for (int j = 0; j < NJ; ++j) {
                const int c_ = wn + j * 16 + ccol;
                const int r_ = wm + i * 16 + crow;      // multiple of 4
                uint2 w;
                w.x = (u32)f32_to_bf16(acc[i][j][0]) | ((u32)f32_to_bf16(acc[i][j][1]) << 16);
                w.y = (u32)f32_to_bf16(acc[i][j][2]) | ((u32)f32_to_bf16(acc[i][j][3]) << 16);
                *(uint2*)&T[c_ * 132 + r_] = w;
            }
        }
        __syncthreads();
        const int cpart = t >> 4;          // 0..15: column within pass
        const int m = t & 15;              // 16 B chunk along the row
#pragma unroll
        for (int k2 = 0; k2 < BNT / 16; ++k2) {
            const int c_ = k2 * 16 + cpart;
            uint2 x = *(const uint2*)&T[c_ * 132 + m * 8];
            uint2 y = *(const uint2*)&T[c_ * 132 + m * 8 + 4];
            uint4 w; w.x = x.x; w.y = x.y; w.z = y.x; w.w = y.y;
            *(uint4*)&op.OutT[(size_t)(bn * BNT + c_) * ldo + bm * BM + m * 8] = w;
        }
    }
}

static inline GemmOp mkop(const u16* U, const u16* V, int K, int ldu, int ldv,
                          const float* Add, u16* OutB, u16* OutT, float* OutF,
                          int N = 2048, int ldo = 2048) {
    GemmOp o;
    o.U = U; o.V = V; o.Add = Add; o.OutB = OutB; o.OutT = OutT; o.OutF = OutF;
    o.K = K; o.ldu = ldu; o.ldv = ldv; o.N = N; o.ldo = ldo;
    return o;
}

extern "C" void kernel_launch(void* const* d_in, const int* in_sizes, int n_in,
                              void* d_out, int out_size, void* d_ws, size_t ws_size,
                              hipStream_t stream) {
    const float* A = (const float*)d_in[0];     // (2048, 2048)
    const float* A_F = (const float*)d_in[1];   // (2048, 2048)
    const float* C = (const float*)d_in[2];     // (512, 2048)
    const float* C_F = (const float*)d_in[3];   // (512, 2048)
    const int n = 2048, p = 512;
    (void)in_sizes; (void)n_in; (void)out_size; (void)ws_size;

    char* ws = (char*)d_ws;
    const size_t MB = 1u << 20;
    // ---- Smith squaring, 5 levels -> S_32 (tail bound: see R12 notes;
    // absmax 0.5 measured, threshold 2.33).
    // d0b-fold: R_1 = [CFT|W1] [CT|Y]^T in ONE K=1024 GEMM.
    // XT computed transpose-free via operand swap:
    //   (R A)^T = NT-GEMM(U = A^T, V = R)  -> plain OutB store.
    // Asq swapped to (U=A^T, V=A) so d1's two z's share the U stream:
    //   OutB = (A^2)^T, OutT = A^2.
    u16* AT   = (u16*)(ws + 0 * MB);    // A^T  bf16  (A_0 transposed form)
    u16* Ab   = (u16*)(ws + 8 * MB);    // A    bf16  (A_0 row form)
    u16* AFT  = (u16*)(ws + 16 * MB);   // B=A_F^T row bf16 (B_0 row form)
    u16* AFb  = (u16*)(ws + 24 * MB);   // A_F  bf16  (B_0 transposed form)
    u16* WYU  = (u16*)(ws + 32 * MB);   // 2048x1024: [CFT | W1=B C_F^T]
    u16* WYV  = (u16*)(ws + 36 * MB);   // 2048x1024: [CT  | Y=A^T C^T]
    u16* XT   = (u16*)(ws + 32 * MB);   // (R A_i)^T — overlaps WYU/WYV (dead after d0b)
    float* R32 = (float*)(ws + 40 * MB);// running R fp32
    u16* Rb   = (u16*)(ws + 56 * MB);   // running R bf16 row
    u16* CFb  = (u16*)(ws + 64 * MB);   // C_F bf16 row (level 0 only)
    u16* Cb   = (u16*)(ws + 66 * MB);   // C   bf16 row (level 0 only)
    u16* Tb1  = (u16*)(ws + 68 * MB);   // ping-pong set 1: B_i row
    u16* TbT1 = (u16*)(ws + 76 * MB);   //                  B_i^T
    u16* Ub1  = (u16*)(ws + 84 * MB);   //                  A_i row
    u16* UbT1 = (u16*)(ws + 92 * MB);   //                  A_i^T   (top = 100 MB)

    dim3 tb(32, 8);
    stein_prep_sq<<<dim3(64, 64), tb, 0, stream>>>(A, Ab, AT, n);
    stein_prep_sq<<<dim3(64, 64), tb, 0, stream>>>(A_F, AFb, AFT, n);
    stein_prep_rect<<<dim3(64, 16), tb, 0, stream>>>(C_F, CFb, WYU, p, n, 2 * p);
    stein_prep_rect<<<dim3(64, 16), tb, 0, stream>>>(C, Cb, WYV, p, n, 2 * p);

    u16* Tb[2]  = {AFT, Tb1};
    u16* TbT[2] = {AFb, TbT1};
    u16* Ub[2]  = {Ab, Ub1};
    u16* UbT[2] = {AT, UbT1};

    dim3 blk(256);
    dim3 g2(16, 16, 2), g4(16, 16, 4);
    dim3 gs(16, 32, 1);                 // BNT=64 single-op grid: 2 blocks/CU

    // d0 (z=4): level-0 independent ops. Long K=2048 small-N ops at LOW z
    // (dispatched first) so stragglers are short.
    {
        GemmOp oW1  = mkop(AFT, CFb, n, n, n, nullptr, WYU + p, nullptr, nullptr, p, 2 * p);
        GemmOp oY   = mkop(AT, Cb, n, n, n, nullptr, WYV + p, nullptr, nullptr, p, 2 * p);
        GemmOp oAsq = mkop(AT, Ab, n, n, n, nullptr, UbT1, Ub1, nullptr);   // swapped
        GemmOp oBsq = mkop(AFT, AFb, n, n, n, nullptr, Tb1, TbT1, nullptr);
        stein_gemm_nt2<128><<<g4, blk, 0, stream>>>(oW1, oY, oAsq, oBsq, oBsq);
    }
    // d0b: R_1 = [CFT|W1] [CT|Y]^T  (K=1024 concat = RHS + B RHS A)
    {
        GemmOp oR1 = mkop(WYU, WYV, 2 * p, 2 * p, 2 * p, nullptr, Rb, nullptr, R32);
        stein_gemm_nt2<64><<<gs, blk, 0, stream>>>(oR1, oR1, oR1, oR1, oR1);
    }

    // levels 1..3: full doubling, stream-sharing pairing.
    // R_j = S_{2^j}; after level 3: R_4 = S_16, A_4 = A^16 in set 0.
    // Level 3 drops dead outputs (level 4 needs only UbT[0] and Tb[0]).
    for (int i = 1; i < 4; ++i) {
        const int c = i & 1, nx = c ^ 1;
        // d1: {XT = (R A_i)^T via swap, Asq swapped} — shared U = A_i^T.
        GemmOp oXT = mkop(UbT[c], Rb, n, n, n, nullptr, XT, nullptr, nullptr);
        GemmOp oAsq = mkop(UbT[c], Ub[c], n, n, n, nullptr, UbT[nx],
                           (i == 3) ? nullptr : Ub[nx], nullptr);
        stein_gemm_nt2<128><<<g2, blk, 0, stream>>>(oXT, oAsq, oAsq, oAsq, oAsq);
        // d2: {Rup = B_i X + R, Bsq = B_i^2} — shared U stream = B_i.
        GemmOp oRup = mkop(Tb[c], XT, n, n, n, R32, Rb, nullptr, R32);
        GemmOp oBsq = mkop(Tb[c], TbT[c], n, n, n, nullptr, Tb[nx],
                           (i == 3) ? nullptr : TbT[nx], nullptr);
        stein_gemm_nt2<128><<<g2, blk, 0, stream>>>(oRup, oBsq, oBsq, oBsq, oBsq);
    }

    // level 4 (final): S_32 = R_4 + B_4 (R_4 A_4) -> d_out. A_4/B_4 in set 0.
    {
        GemmOp oXT = mkop(UbT[0], Rb, n, n, n, nullptr, XT, nullptr, nullptr);
        stein_gemm_nt2<64><<<gs, blk, 0, stream>>>(oXT, oXT, oXT, oXT, oXT);
        GemmOp oFin = mkop(Tb[0], XT, n, n, n, R32, nullptr, nullptr, (float*)d_out);
        stein_gemm_nt2<64><<<gs, blk, 0, stream>>>(oFin, oFin, oFin, oFin, oFin);
    }
}